// Round 1
// baseline (158.268 us; speedup 1.0000x reference)
//
#include <hip/hip_runtime.h>
#include <math.h>

#define NTOT   12
#define DIM    4096      // 2^12
#define LAYERS 4
#define NPOST  256       // 2^8 post-measurement dim
#define NANC   16        // 2^4 ancilla outcomes
#define NB     1024      // batch

// One block per batch sample. State (re/im) lives in LDS (32 KB -> ~4 blocks/CU).
__global__ __launch_bounds__(256) void qddpm_kernel(
    const float* __restrict__ in_re,
    const float* __restrict__ in_im,
    const float* __restrict__ params,
    const float* __restrict__ uu,
    float* __restrict__ out)
{
    __shared__ float sre[DIM];
    __shared__ float sim[DIM];
    __shared__ float gc[2 * NTOT * LAYERS];   // cos(theta/2) for all 96 params
    __shared__ float gs[2 * NTOT * LAYERS];   // sin(theta/2)
    __shared__ float sprob[NANC];
    __shared__ int   ssel;
    __shared__ float srnorm;

    const int b = blockIdx.x;
    const int t = threadIdx.x;

    // ---- load state (coalesced float4) + precompute gate cos/sin ----
    {
        const float4* re4 = (const float4*)(in_re + (size_t)b * DIM);
        const float4* im4 = (const float4*)(in_im + (size_t)b * DIM);
        float4* sre4 = (float4*)sre;
        float4* sim4 = (float4*)sim;
#pragma unroll
        for (int k = 0; k < 4; ++k) {
            int idx = k * 256 + t;           // 1024 float4 = 4096 floats
            sre4[idx] = re4[idx];
            sim4[idx] = im4[idx];
        }
        if (t < 2 * NTOT * LAYERS) {
            float th = params[t] * 0.5f;
            float s, c;
            sincosf(th, &s, &c);
            gc[t] = c; gs[t] = s;
        }
    }
    __syncthreads();

    // ---- circuit: per layer, per qubit one fused (Ry*Rx) pass; CZ folded into q==11 write ----
    for (int lay = 0; lay < LAYERS; ++lay) {
        const int off = 2 * NTOT * lay;
        for (int q = 0; q < NTOT; ++q) {
            const float c1 = gc[off + q],        s1 = gs[off + q];
            const float c2 = gc[off + NTOT + q], s2 = gs[off + NTOT + q];
            // combined U = Ry(th2) * Rx(th1):
            const float a_re =  c1 * c2, a_im =  s1 * s2;   // U00
            const float b_re = -c1 * s2, b_im = -s1 * c2;   // U01
            const float d_re =  c1 * s2, d_im = -s1 * c2;   // U10
            const float e_re =  c1 * c2, e_im = -s1 * s2;   // U11
            const int shift = NTOT - 1 - q;    // qubit 0 = MSB
            const int r = 1 << shift;
            const bool last = (q == NTOT - 1);
#pragma unroll
            for (int k = 0; k < 8; ++k) {
                const int p  = k * 256 + t;                       // 2048 pairs
                const int i0 = ((p >> shift) << (shift + 1)) | (p & (r - 1));
                const int i1 = i0 | r;
                const float x0r = sre[i0], x0i = sim[i0];
                const float x1r = sre[i1], x1i = sim[i1];
                float n0r = a_re * x0r - a_im * x0i + b_re * x1r - b_im * x1i;
                float n0i = a_re * x0i + a_im * x0r + b_re * x1i + b_im * x1r;
                float n1r = d_re * x0r - d_im * x0i + e_re * x1r - e_im * x1i;
                float n1i = d_re * x0i + d_im * x0r + e_re * x1i + e_im * x1r;
                if (last) {
                    // CZ brick diagonal: all 11 adjacent-qubit pairs -> parity of i&(i>>1)
                    const float sg0 = 1.0f - 2.0f * (float)(__popc(i0 & (i0 >> 1) & 0x7FF) & 1);
                    const float sg1 = 1.0f - 2.0f * (float)(__popc(i1 & (i1 >> 1) & 0x7FF) & 1);
                    n0r *= sg0; n0i *= sg0; n1r *= sg1; n1i *= sg1;
                }
                sre[i0] = n0r; sim[i0] = n0i;
                sre[i1] = n1r; sim[i1] = n1i;
            }
            __syncthreads();
        }
    }

    // ---- ancilla outcome probabilities: thread t owns elements [16t, 16t+16) (one outcome) ----
    float partial = 0.0f;
    {
        const float4* sre4 = (const float4*)sre;
        const float4* sim4 = (const float4*)sim;
#pragma unroll
        for (int k = 0; k < 4; ++k) {
            const float4 vr = sre4[t * 4 + k];
            const float4 vi = sim4[t * 4 + k];
            partial += vr.x * vr.x + vr.y * vr.y + vr.z * vr.z + vr.w * vr.w;
            partial += vi.x * vi.x + vi.y * vi.y + vi.z * vi.z + vi.w * vi.w;
        }
    }
#pragma unroll
    for (int o = 8; o > 0; o >>= 1)
        partial += __shfl_down(partial, o, 16);
    if ((t & 15) == 0) sprob[t >> 4] = partial;
    __syncthreads();

    // ---- inverse-CDF sample + norm (serial over 16 outcomes on thread 0) ----
    if (t == 0) {
        float cdf[NANC];
        float acc = 0.0f;
#pragma unroll
        for (int i = 0; i < NANC; ++i) { acc += sprob[i]; cdf[i] = acc; }
        const float thresh = uu[b] * acc;
        int m = 0;
        for (int i = 0; i < NANC; ++i) { if (cdf[i] >= thresh) { m = i; break; } }
        ssel = m;
        srnorm = 1.0f / sqrtf(sprob[m]);
    }
    __syncthreads();

    // ---- collapsed, normalized state out: [B, 256, 2] interleaved re/im ----
    {
        const int m = ssel;
        const float rn = srnorm;
        const float pr = sre[m * NPOST + t] * rn;
        const float pi = sim[m * NPOST + t] * rn;
        ((float2*)out)[(size_t)b * NPOST + t] = make_float2(pr, pi);
    }
}

extern "C" void kernel_launch(void* const* d_in, const int* in_sizes, int n_in,
                              void* d_out, int out_size, void* d_ws, size_t ws_size,
                              hipStream_t stream) {
    const float* in_re  = (const float*)d_in[0];
    const float* in_im  = (const float*)d_in[1];
    const float* params = (const float*)d_in[2];
    const float* u      = (const float*)d_in[3];
    float* out = (float*)d_out;
    qddpm_kernel<<<NB, 256, 0, stream>>>(in_re, in_im, params, u, out);
}

// Round 2
// 117.583 us; speedup vs baseline: 1.3460x; 1.3460x over previous
//
#include <hip/hip_runtime.h>
#include <math.h>

#define NTOT   12
#define DIM    4096      // 2^12
#define LAYERS 4
#define NB     1024      // batch

// Bank-conflict-killing bijective LDS layout: logical amp i -> phys slot.
// Verified: stride-256 (pass A), stride-16 (pass B), contiguous-16 (pass C)
// access patterns all land 2 lanes/bank (free) under this map.
__device__ __forceinline__ int PHYS(int i) {
    return i ^ ((i >> 5) & 15) ^ (((i >> 9) & 1) << 4);
}

// Fused (Ry*Rx) gate on local bit G of a 16-amp register block.
// U00 = cc + i*ss, U01 = -cs - i*sc, U10 = cs - i*sc, U11 = cc - i*ss
template<int G>
__device__ __forceinline__ void gate2(float (&xr)[16], float (&xi)[16],
                                      float cc, float ss, float cs, float sc) {
#pragma unroll
    for (int p = 0; p < 8; ++p) {
        const int j0 = ((p >> G) << (G + 1)) | (p & ((1 << G) - 1));
        const int j1 = j0 | (1 << G);
        const float x0r = xr[j0], x0i = xi[j0];
        const float x1r = xr[j1], x1i = xi[j1];
        xr[j0] = cc * x0r - ss * x0i - cs * x1r + sc * x1i;
        xi[j0] = cc * x0i + ss * x0r - cs * x1i - sc * x1r;
        xr[j1] = cs * x0r + sc * x0i + cc * x1r + ss * x1i;
        xi[j1] = cs * x0i - sc * x0r + cc * x1i - ss * x1r;
    }
}

__global__ __launch_bounds__(256, 4) void qddpm_kernel(
    const float* __restrict__ in_re,
    const float* __restrict__ in_im,
    const float* __restrict__ params,
    const float* __restrict__ uu,
    float* __restrict__ out)
{
    __shared__ float S[2 * DIM];            // [0..4095]=re, [4096..8191]=im (phys layout)
    __shared__ float CC[48], SS[48], CS[48], SC[48];  // per-gate products, g = lay*12+q
    __shared__ float sprob[16];
    __shared__ int   ssel;
    __shared__ float srnorm;

    const int b = blockIdx.x;
    const int t = threadIdx.x;

    // ---- initial load (global float4, coalesced) -> LDS scatter + coeff precompute ----
    {
        const float4* re4 = (const float4*)(in_re + (size_t)b * DIM);
        const float4* im4 = (const float4*)(in_im + (size_t)b * DIM);
#pragma unroll
        for (int k = 0; k < 4; ++k) {
            const int g = k * 256 + t;       // 1024 float4 groups
            const float4 vr = re4[g];
            const float4 vi = im4[g];
            const int i0 = g * 4;
            S[PHYS(i0 + 0)] = vr.x; S[PHYS(i0 + 1)] = vr.y;
            S[PHYS(i0 + 2)] = vr.z; S[PHYS(i0 + 3)] = vr.w;
            S[DIM + PHYS(i0 + 0)] = vi.x; S[DIM + PHYS(i0 + 1)] = vi.y;
            S[DIM + PHYS(i0 + 2)] = vi.z; S[DIM + PHYS(i0 + 3)] = vi.w;
        }
        if (t < 48) {                        // gate (lay = t/12, q = t%12)
            const int lay = t / 12, q = t - lay * 12;
            float c1, s1, c2, s2;
            sincosf(params[lay * 24 + q] * 0.5f, &s1, &c1);
            sincosf(params[lay * 24 + 12 + q] * 0.5f, &s2, &c2);
            CC[t] = c1 * c2; SS[t] = s1 * s2;
            CS[t] = c1 * s2; SC[t] = s1 * c2;
        }
    }
    __syncthreads();

    // per-thread constants for the three pass address patterns
    const int u    = t ^ (t >> 5);                 // pass A base
    const int hi   = t >> 4, lo = t & 15;
    const int basB = hi * 256 + lo;                // pass B
    const int xmB  = (hi & 3) << 3;
    const int basC = (t * 16) ^ ((t & 32) >> 1);   // pass C
    const int wC   = (t >> 1) & 15;

    // CZ-diag sign mask for this thread's pass-C amps (i = t*16+j), fixed across layers
    int smask = 0;
#pragma unroll
    for (int j = 0; j < 16; ++j) {
        const int i = t * 16 + j;
        smask |= (__popc(i & (i >> 1) & 0x7FF) & 1) << j;
    }

    float xr[16], xi[16];
    float partial = 0.0f;

    for (int lay = 0; lay < LAYERS; ++lay) {
        const int gb = lay * 12;

        // ---- pass A: qubits 0..3 (amp bits 8..11), local bit g -> qubit 3-g ----
#pragma unroll
        for (int j = 0; j < 16; ++j) {
            const int p = j * 256 + (u ^ ((j & 3) << 3));
            xr[j] = S[p]; xi[j] = S[DIM + p];
        }
        gate2<0>(xr, xi, CC[gb + 3], SS[gb + 3], CS[gb + 3], SC[gb + 3]);
        gate2<1>(xr, xi, CC[gb + 2], SS[gb + 2], CS[gb + 2], SC[gb + 2]);
        gate2<2>(xr, xi, CC[gb + 1], SS[gb + 1], CS[gb + 1], SC[gb + 1]);
        gate2<3>(xr, xi, CC[gb + 0], SS[gb + 0], CS[gb + 0], SC[gb + 0]);
#pragma unroll
        for (int j = 0; j < 16; ++j) {
            const int p = j * 256 + (u ^ ((j & 3) << 3));
            S[p] = xr[j]; S[DIM + p] = xi[j];
        }
        __syncthreads();

        // ---- pass B: qubits 4..7 (amp bits 4..7), local bit g -> qubit 7-g ----
#pragma unroll
        for (int j = 0; j < 16; ++j) {
            const int p = ((basB + j * 16) ^ xmB) ^ (j >> 1);
            xr[j] = S[p]; xi[j] = S[DIM + p];
        }
        gate2<0>(xr, xi, CC[gb + 7], SS[gb + 7], CS[gb + 7], SC[gb + 7]);
        gate2<1>(xr, xi, CC[gb + 6], SS[gb + 6], CS[gb + 6], SC[gb + 6]);
        gate2<2>(xr, xi, CC[gb + 5], SS[gb + 5], CS[gb + 5], SC[gb + 5]);
        gate2<3>(xr, xi, CC[gb + 4], SS[gb + 4], CS[gb + 4], SC[gb + 4]);
#pragma unroll
        for (int j = 0; j < 16; ++j) {
            const int p = ((basB + j * 16) ^ xmB) ^ (j >> 1);
            S[p] = xr[j]; S[DIM + p] = xi[j];
        }
        __syncthreads();

        // ---- pass C: qubits 8..11 (amp bits 0..3), local bit g -> qubit 11-g; + CZ ----
#pragma unroll
        for (int j = 0; j < 16; ++j) {
            const int p = basC + (j ^ wC);
            xr[j] = S[p]; xi[j] = S[DIM + p];
        }
        gate2<0>(xr, xi, CC[gb + 11], SS[gb + 11], CS[gb + 11], SC[gb + 11]);
        gate2<1>(xr, xi, CC[gb + 10], SS[gb + 10], CS[gb + 10], SC[gb + 10]);
        gate2<2>(xr, xi, CC[gb +  9], SS[gb +  9], CS[gb +  9], SC[gb +  9]);
        gate2<3>(xr, xi, CC[gb +  8], SS[gb +  8], CS[gb +  8], SC[gb +  8]);
#pragma unroll
        for (int j = 0; j < 16; ++j) {
            if (smask & (1 << j)) { xr[j] = -xr[j]; xi[j] = -xi[j]; }
        }
#pragma unroll
        for (int j = 0; j < 16; ++j) {
            const int p = basC + (j ^ wC);
            S[p] = xr[j]; S[DIM + p] = xi[j];
        }
        if (lay == LAYERS - 1) {
            // this thread's 16 amps (i = t*16..t*16+15) all belong to outcome t>>4
#pragma unroll
            for (int j = 0; j < 16; ++j)
                partial += xr[j] * xr[j] + xi[j] * xi[j];
        }
        __syncthreads();
    }

    // ---- ancilla outcome probs: reduce over the 16 threads sharing outcome t>>4 ----
#pragma unroll
    for (int o = 8; o > 0; o >>= 1)
        partial += __shfl_down(partial, o, 16);
    if ((t & 15) == 0) sprob[t >> 4] = partial;
    __syncthreads();

    // ---- inverse-CDF sample + norm (thread 0) ----
    if (t == 0) {
        float cdf[16];
        float acc = 0.0f;
#pragma unroll
        for (int i = 0; i < 16; ++i) { acc += sprob[i]; cdf[i] = acc; }
        const float thresh = uu[b] * acc;
        int m = 0;
        for (int i = 0; i < 16; ++i) { if (cdf[i] >= thresh) { m = i; break; } }
        ssel = m;
        srnorm = 1.0f / sqrtf(sprob[m]);
    }
    __syncthreads();

    // ---- collapsed, normalized state out: [B, 256, 2] ----
    {
        const int m = ssel;
        const float rn = srnorm;
        const int p = m * 256 + (u ^ ((m & 3) << 3));   // pass-A pattern, conflict-free
        ((float2*)out)[(size_t)b * 256 + t] = make_float2(S[p] * rn, S[DIM + p] * rn);
    }
}

extern "C" void kernel_launch(void* const* d_in, const int* in_sizes, int n_in,
                              void* d_out, int out_size, void* d_ws, size_t ws_size,
                              hipStream_t stream) {
    const float* in_re  = (const float*)d_in[0];
    const float* in_im  = (const float*)d_in[1];
    const float* params = (const float*)d_in[2];
    const float* u      = (const float*)d_in[3];
    float* out = (float*)d_out;
    qddpm_kernel<<<NB, 256, 0, stream>>>(in_re, in_im, params, u, out);
}

// Round 3
// 117.535 us; speedup vs baseline: 1.3466x; 1.0004x over previous
//
#include <hip/hip_runtime.h>
#include <math.h>

#define NTOT   12
#define DIM    4096      // 2^12
#define LAYERS 4
#define NB     1024      // batch

typedef float v2f __attribute__((ext_vector_type(2)));

// multiply by i: (r,i) -> (-i, r)
__device__ __forceinline__ v2f ixv(v2f x) { return (v2f){ -x.y, x.x }; }

// Fused (Ry*Rx) on local bit G of a 16-amp register block (complex interleaved).
// U00 = cc + i*ss, U01 = -cs - i*sc, U10 = cs - i*sc, U11 = cc - i*ss
template<int G>
__device__ __forceinline__ void gate2(v2f (&x)[16], float cc, float ss, float cs, float sc) {
#pragma unroll
    for (int p = 0; p < 8; ++p) {
        const int j0 = ((p >> G) << (G + 1)) | (p & ((1 << G) - 1));
        const int j1 = j0 | (1 << G);
        const v2f x0 = x[j0], x1 = x[j1];
        const v2f ix0 = ixv(x0), ix1 = ixv(x1);
        x[j0] = cc * x0 + ss * ix0 - cs * x1 - sc * ix1;
        x[j1] = cs * x0 - sc * ix0 + cc * x1 - ss * ix1;
    }
}

// Bank swizzle: phys(i) = i ^ ((i>>4)&15).  For every access pattern in this
// kernel the 64 lanes of a wave hit each 8B bank-pair exactly 4x per b64 op
// (the LDS floor: 512B / 128B-per-cycle).
__global__ __launch_bounds__(256, 4) void qddpm_kernel(
    const float* __restrict__ in_re,
    const float* __restrict__ in_im,
    const float* __restrict__ params,
    const float* __restrict__ uu,
    float* __restrict__ out)
{
    __shared__ v2f    S[DIM];          // 32 KB, interleaved (re,im), phys-swizzled
    __shared__ float4 gco[48];         // per-gate (cc,ss,cs,sc), g = lay*12+q
    __shared__ float  sprob[16];
    __shared__ int    ssel;
    __shared__ float  srnorm;

    const int b = blockIdx.x;
    const int t = threadIdx.x;

    // ---- init: coalesced float4 global loads -> interleaved swizzled LDS ----
    {
        const float4* re4 = (const float4*)(in_re + (size_t)b * DIM);
        const float4* im4 = (const float4*)(in_im + (size_t)b * DIM);
#pragma unroll
        for (int k = 0; k < 4; ++k) {
            const int g  = k * 256 + t;          // float4 group, amps i0..i0+3
            const float4 vr = re4[g];
            const float4 vi = im4[g];
            const int i0 = g * 4;
            const int pb = i0 ^ ((i0 >> 4) & 15);  // phys(i0+e) = pb ^ e
            S[pb ^ 0] = (v2f){vr.x, vi.x};
            S[pb ^ 1] = (v2f){vr.y, vi.y};
            S[pb ^ 2] = (v2f){vr.z, vi.z};
            S[pb ^ 3] = (v2f){vr.w, vi.w};
        }
        if (t < 48) {                    // gate (lay = t/12, q = t%12)
            const int lay = t / 12, q = t - lay * 12;
            float c1, s1, c2, s2;
            sincosf(params[lay * 24 + q] * 0.5f, &s1, &c1);
            sincosf(params[lay * 24 + 12 + q] * 0.5f, &s2, &c2);
            gco[t] = make_float4(c1 * c2, s1 * s2, c1 * s2, s1 * c2);
        }
    }
    __syncthreads();

    // per-thread address bases
    const int baseA = t ^ ((t >> 4) & 15);   // pass A: phys = j*256 + baseA
    const int hiB = t >> 4, loB = t & 15;    // pass B: phys = hiB*256 + j*16 + (loB^j)
    const int baseC = t * 16, mC = t & 15;   // pass C: phys = baseC + (j^mC)

    // CZ-diag sign mask for this thread's pass-C amps (i = t*16+j)
    int smask = 0;
#pragma unroll
    for (int j = 0; j < 16; ++j) {
        const int i = t * 16 + j;
        smask |= (__popc(i & (i >> 1) & 0x7FF) & 1) << j;
    }

    v2f x[16];
    v2f acc2 = (v2f){0.0f, 0.0f};

#pragma unroll
    for (int lay = 0; lay < LAYERS; ++lay) {
        const int gb = lay * 12;

        // ---- pass A: amp bits 11:8 (qubits 0..3) ----
#pragma unroll
        for (int j = 0; j < 16; ++j) x[j] = S[j * 256 + baseA];
        { float4 c;
          c = gco[gb + 3]; gate2<0>(x, c.x, c.y, c.z, c.w);
          c = gco[gb + 2]; gate2<1>(x, c.x, c.y, c.z, c.w);
          c = gco[gb + 1]; gate2<2>(x, c.x, c.y, c.z, c.w);
          c = gco[gb + 0]; gate2<3>(x, c.x, c.y, c.z, c.w); }
#pragma unroll
        for (int j = 0; j < 16; ++j) S[j * 256 + baseA] = x[j];
        __syncthreads();

        // ---- pass B: amp bits 7:4 (qubits 4..7) ----
#pragma unroll
        for (int j = 0; j < 16; ++j) x[j] = S[hiB * 256 + j * 16 + (loB ^ j)];
        { float4 c;
          c = gco[gb + 7]; gate2<0>(x, c.x, c.y, c.z, c.w);
          c = gco[gb + 6]; gate2<1>(x, c.x, c.y, c.z, c.w);
          c = gco[gb + 5]; gate2<2>(x, c.x, c.y, c.z, c.w);
          c = gco[gb + 4]; gate2<3>(x, c.x, c.y, c.z, c.w); }
#pragma unroll
        for (int j = 0; j < 16; ++j) S[hiB * 256 + j * 16 + (loB ^ j)] = x[j];
        __syncthreads();

        // ---- pass C: amp bits 3:0 (qubits 8..11) + CZ diag ----
#pragma unroll
        for (int j = 0; j < 16; ++j) x[j] = S[baseC + (j ^ mC)];
        { float4 c;
          c = gco[gb + 11]; gate2<0>(x, c.x, c.y, c.z, c.w);
          c = gco[gb + 10]; gate2<1>(x, c.x, c.y, c.z, c.w);
          c = gco[gb +  9]; gate2<2>(x, c.x, c.y, c.z, c.w);
          c = gco[gb +  8]; gate2<3>(x, c.x, c.y, c.z, c.w); }
#pragma unroll
        for (int j = 0; j < 16; ++j) {
            if (smask & (1 << j)) x[j] = -x[j];
        }
        if (lay == LAYERS - 1) {
#pragma unroll
            for (int j = 0; j < 16; ++j) acc2 += x[j] * x[j];
        }
#pragma unroll
        for (int j = 0; j < 16; ++j) S[baseC + (j ^ mC)] = x[j];
        __syncthreads();
    }

    // ---- ancilla outcome probs (this thread's 16 amps all in outcome t>>4) ----
    float partial = acc2.x + acc2.y;
#pragma unroll
    for (int o = 8; o > 0; o >>= 1)
        partial += __shfl_down(partial, o, 16);
    if ((t & 15) == 0) sprob[t >> 4] = partial;
    __syncthreads();

    // ---- inverse-CDF sample + norm (thread 0) ----
    if (t == 0) {
        float cdf[16];
        float a = 0.0f;
#pragma unroll
        for (int i = 0; i < 16; ++i) { a += sprob[i]; cdf[i] = a; }
        const float thresh = uu[b] * a;
        int m = 0;
        for (int i = 0; i < 16; ++i) { if (cdf[i] >= thresh) { m = i; break; } }
        ssel = m;
        srnorm = 1.0f / sqrtf(sprob[m]);
    }
    __syncthreads();

    // ---- collapsed, normalized output: [B, 256, 2] ----
    {
        const int m = ssel;
        const float rn = srnorm;
        const v2f a = S[m * 256 + baseA];   // phys(m*256+t), pass-A pattern
        ((float2*)out)[(size_t)b * 256 + t] = make_float2(a.x * rn, a.y * rn);
    }
}

extern "C" void kernel_launch(void* const* d_in, const int* in_sizes, int n_in,
                              void* d_out, int out_size, void* d_ws, size_t ws_size,
                              hipStream_t stream) {
    const float* in_re  = (const float*)d_in[0];
    const float* in_im  = (const float*)d_in[1];
    const float* params = (const float*)d_in[2];
    const float* u      = (const float*)d_in[3];
    float* out = (float*)d_out;
    qddpm_kernel<<<NB, 256, 0, stream>>>(in_re, in_im, params, u, out);
}

// Round 4
// 111.589 us; speedup vs baseline: 1.4183x; 1.0533x over previous
//
#include <hip/hip_runtime.h>
#include <math.h>

#define NTOT   12
#define DIM    4096      // 2^12
#define LAYERS 4
#define NB     1024      // batch

typedef float v2f __attribute__((ext_vector_type(2)));

// Fused (Ry*Rx) SU(2) gate on local bit G of a 16-amp register block, complex
// interleaved (lo=re, hi=im). Coefficients packed: P1=(cc,cs), P2=(ss,sc).
//   y0.re = cc*x0r - ss*x0i - cs*x1r + sc*x1i
//   y0.im = cc*x0i + ss*x0r - cs*x1i - sc*x1r
//   y1.re = cs*x0r + sc*x0i + cc*x1r + ss*x1i
//   y1.im = cs*x0i - sc*x0r + cc*x1i - ss*x1r
// 8 v_pk_*_f32 per pair; swaps/negs done via op_sel / neg modifiers.
template<int G>
__device__ __forceinline__ void gate_pk(v2f (&x)[16], v2f P1, v2f P2) {
#pragma unroll
    for (int p = 0; p < 8; ++p) {
        const int j0 = ((p >> G) << (G + 1)) | (p & ((1 << G) - 1));
        const int j1 = j0 | (1 << G);
        const v2f x0 = x[j0], x1 = x[j1];
        v2f t, u;
        // ---- y0 ----
        // t = (sc*x1i, -sc*x1r)
        asm("v_pk_mul_f32 %0, %1, %2 op_sel:[1,1] op_sel_hi:[1,0] neg_hi:[1,0]"
            : "=v"(t) : "v"(P2), "v"(x1));
        // t += (-cs*x1r, -cs*x1i)
        asm("v_pk_fma_f32 %0, %1, %2, %0 op_sel:[1,0,0] op_sel_hi:[1,1,1] neg_lo:[1,0,0] neg_hi:[1,0,0]"
            : "+v"(t) : "v"(P1), "v"(x1));
        // t += (-ss*x0i, ss*x0r)
        asm("v_pk_fma_f32 %0, %1, %2, %0 op_sel:[0,1,0] op_sel_hi:[0,0,1] neg_lo:[1,0,0]"
            : "+v"(t) : "v"(P2), "v"(x0));
        // t += (cc*x0r, cc*x0i)
        asm("v_pk_fma_f32 %0, %1, %2, %0 op_sel:[0,0,0] op_sel_hi:[0,1,1]"
            : "+v"(t) : "v"(P1), "v"(x0));
        // ---- y1 ----
        // u = (ss*x1i, -ss*x1r)
        asm("v_pk_mul_f32 %0, %1, %2 op_sel:[0,1] op_sel_hi:[0,0] neg_hi:[1,0]"
            : "=v"(u) : "v"(P2), "v"(x1));
        // u += (cc*x1r, cc*x1i)
        asm("v_pk_fma_f32 %0, %1, %2, %0 op_sel:[0,0,0] op_sel_hi:[0,1,1]"
            : "+v"(u) : "v"(P1), "v"(x1));
        // u += (sc*x0i, -sc*x0r)
        asm("v_pk_fma_f32 %0, %1, %2, %0 op_sel:[1,1,0] op_sel_hi:[1,0,1] neg_hi:[1,0,0]"
            : "+v"(u) : "v"(P2), "v"(x0));
        // u += (cs*x0r, cs*x0i)
        asm("v_pk_fma_f32 %0, %1, %2, %0 op_sel:[1,0,0] op_sel_hi:[1,1,1]"
            : "+v"(u) : "v"(P1), "v"(x0));
        x[j0] = t; x[j1] = u;
    }
}

// Bank swizzle: phys(i) = i ^ ((i>>4)&15) — all pass patterns land 4 lanes
// per 8B bank-pair per b64 op (the LDS floor).
__global__ __launch_bounds__(256, 4) void qddpm_kernel(
    const float* __restrict__ in_re,
    const float* __restrict__ in_im,
    const float* __restrict__ params,
    const float* __restrict__ uu,
    float* __restrict__ out)
{
    __shared__ v2f    S[DIM];          // 32 KB, interleaved (re,im), phys-swizzled
    __shared__ float4 gco[48];         // per-gate (cc, cs, ss, sc), g = lay*12+q
    __shared__ float  sprob[16];
    __shared__ int    ssel;
    __shared__ float  srnorm;

    const int b = blockIdx.x;
    const int t = threadIdx.x;

    // ---- init: coalesced float4 global loads -> interleaved swizzled LDS ----
    {
        const float4* re4 = (const float4*)(in_re + (size_t)b * DIM);
        const float4* im4 = (const float4*)(in_im + (size_t)b * DIM);
#pragma unroll
        for (int k = 0; k < 4; ++k) {
            const int g  = k * 256 + t;          // float4 group, amps i0..i0+3
            const float4 vr = re4[g];
            const float4 vi = im4[g];
            const int i0 = g * 4;
            const int pb = i0 ^ ((i0 >> 4) & 15);  // phys(i0+e) = pb ^ e (pb%4==0)
            S[pb ^ 0] = (v2f){vr.x, vi.x};
            S[pb ^ 1] = (v2f){vr.y, vi.y};
            S[pb ^ 2] = (v2f){vr.z, vi.z};
            S[pb ^ 3] = (v2f){vr.w, vi.w};
        }
        if (t < 48) {                    // gate (lay = t/12, q = t%12)
            const int lay = t / 12, q = t - lay * 12;
            float c1, s1, c2, s2;
            sincosf(params[lay * 24 + q] * 0.5f, &s1, &c1);
            sincosf(params[lay * 24 + 12 + q] * 0.5f, &s2, &c2);
            gco[t] = make_float4(c1 * c2, c1 * s2, s1 * s2, s1 * c2); // (cc,cs,ss,sc)
        }
    }
    __syncthreads();

    // per-thread address bases
    const int baseA = t ^ ((t >> 4) & 15);   // pass A: phys = j*256 + baseA
    const int hiB = t >> 4, loB = t & 15;    // pass B: phys = hiB*256 + j*16 + (loB^j)
    const int baseC = t * 16, mC = t & 15;   // pass C: phys = baseC + (j^mC)

    // CZ-diag sign mask for this thread's pass-C amps (i = t*16+j)
    int smask = 0;
#pragma unroll
    for (int j = 0; j < 16; ++j) {
        const int i = t * 16 + j;
        smask |= (__popc(i & (i >> 1) & 0x7FF) & 1) << j;
    }

    v2f x[16];
    v2f acc2 = (v2f){0.0f, 0.0f};

#pragma unroll 1                        // keep body ~1 layer: fits L1I
    for (int lay = 0; lay < LAYERS; ++lay) {
        const int gb = lay * 12;

        // ---- pass A: amp bits 11:8 (qubits 0..3) ----
#pragma unroll
        for (int j = 0; j < 16; ++j) x[j] = S[j * 256 + baseA];
        { float4 c;
          c = gco[gb + 3]; gate_pk<0>(x, (v2f){c.x,c.y}, (v2f){c.z,c.w});
          c = gco[gb + 2]; gate_pk<1>(x, (v2f){c.x,c.y}, (v2f){c.z,c.w});
          c = gco[gb + 1]; gate_pk<2>(x, (v2f){c.x,c.y}, (v2f){c.z,c.w});
          c = gco[gb + 0]; gate_pk<3>(x, (v2f){c.x,c.y}, (v2f){c.z,c.w}); }
#pragma unroll
        for (int j = 0; j < 16; ++j) S[j * 256 + baseA] = x[j];
        __syncthreads();

        // ---- pass B: amp bits 7:4 (qubits 4..7) ----
#pragma unroll
        for (int j = 0; j < 16; ++j) x[j] = S[hiB * 256 + j * 16 + (loB ^ j)];
        { float4 c;
          c = gco[gb + 7]; gate_pk<0>(x, (v2f){c.x,c.y}, (v2f){c.z,c.w});
          c = gco[gb + 6]; gate_pk<1>(x, (v2f){c.x,c.y}, (v2f){c.z,c.w});
          c = gco[gb + 5]; gate_pk<2>(x, (v2f){c.x,c.y}, (v2f){c.z,c.w});
          c = gco[gb + 4]; gate_pk<3>(x, (v2f){c.x,c.y}, (v2f){c.z,c.w}); }
#pragma unroll
        for (int j = 0; j < 16; ++j) S[hiB * 256 + j * 16 + (loB ^ j)] = x[j];
        __syncthreads();

        // ---- pass C: amp bits 3:0 (qubits 8..11) + CZ diag ----
#pragma unroll
        for (int j = 0; j < 16; ++j) x[j] = S[baseC + (j ^ mC)];
        { float4 c;
          c = gco[gb + 11]; gate_pk<0>(x, (v2f){c.x,c.y}, (v2f){c.z,c.w});
          c = gco[gb + 10]; gate_pk<1>(x, (v2f){c.x,c.y}, (v2f){c.z,c.w});
          c = gco[gb +  9]; gate_pk<2>(x, (v2f){c.x,c.y}, (v2f){c.z,c.w});
          c = gco[gb +  8]; gate_pk<3>(x, (v2f){c.x,c.y}, (v2f){c.z,c.w}); }
#pragma unroll
        for (int j = 0; j < 16; ++j) {
            if (smask & (1 << j)) x[j] = -x[j];
        }
        if (lay == LAYERS - 1) {
#pragma unroll
            for (int j = 0; j < 16; ++j) acc2 += x[j] * x[j];
        }
#pragma unroll
        for (int j = 0; j < 16; ++j) S[baseC + (j ^ mC)] = x[j];
        __syncthreads();
    }

    // ---- ancilla outcome probs (this thread's 16 amps all in outcome t>>4) ----
    float partial = acc2.x + acc2.y;
#pragma unroll
    for (int o = 8; o > 0; o >>= 1)
        partial += __shfl_down(partial, o, 16);
    if ((t & 15) == 0) sprob[t >> 4] = partial;
    __syncthreads();

    // ---- inverse-CDF sample + norm (thread 0) ----
    if (t == 0) {
        float cdf[16];
        float a = 0.0f;
#pragma unroll
        for (int i = 0; i < 16; ++i) { a += sprob[i]; cdf[i] = a; }
        const float thresh = uu[b] * a;
        int m = 0;
        for (int i = 0; i < 16; ++i) { if (cdf[i] >= thresh) { m = i; break; } }
        ssel = m;
        srnorm = 1.0f / sqrtf(sprob[m]);
    }
    __syncthreads();

    // ---- collapsed, normalized output: [B, 256, 2] ----
    {
        const int m = ssel;
        const float rn = srnorm;
        const v2f a = S[m * 256 + baseA];   // phys(m*256+t), pass-A pattern
        ((float2*)out)[(size_t)b * 256 + t] = make_float2(a.x * rn, a.y * rn);
    }
}

extern "C" void kernel_launch(void* const* d_in, const int* in_sizes, int n_in,
                              void* d_out, int out_size, void* d_ws, size_t ws_size,
                              hipStream_t stream) {
    const float* in_re  = (const float*)d_in[0];
    const float* in_im  = (const float*)d_in[1];
    const float* params = (const float*)d_in[2];
    const float* u      = (const float*)d_in[3];
    float* out = (float*)d_out;
    qddpm_kernel<<<NB, 256, 0, stream>>>(in_re, in_im, params, u, out);
}

// Round 5
// 110.831 us; speedup vs baseline: 1.4280x; 1.0068x over previous
//
#include <hip/hip_runtime.h>
#include <math.h>

#define NTOT   12
#define DIM    4096      // 2^12
#define LAYERS 4
#define NB     1024      // batch
#define SPAD   4608      // max phys = 4095 + 2*255 = 4605

typedef float v2f __attribute__((ext_vector_type(2)));

// Fused (Ry*Rx) SU(2) gate on local bit G of a 16-amp register block, complex
// interleaved (lo=re, hi=im). Coefficients packed: P1=(cc,cs), P2=(ss,sc).
// 8 v_pk_*_f32 per pair; swaps/negs via op_sel / neg modifiers.
template<int G>
__device__ __forceinline__ void gate_pk(v2f (&x)[16], v2f P1, v2f P2) {
#pragma unroll
    for (int p = 0; p < 8; ++p) {
        const int j0 = ((p >> G) << (G + 1)) | (p & ((1 << G) - 1));
        const int j1 = j0 | (1 << G);
        const v2f x0 = x[j0], x1 = x[j1];
        v2f t, u;
        asm("v_pk_mul_f32 %0, %1, %2 op_sel:[1,1] op_sel_hi:[1,0] neg_hi:[1,0]"
            : "=v"(t) : "v"(P2), "v"(x1));
        asm("v_pk_fma_f32 %0, %1, %2, %0 op_sel:[1,0,0] op_sel_hi:[1,1,1] neg_lo:[1,0,0] neg_hi:[1,0,0]"
            : "+v"(t) : "v"(P1), "v"(x1));
        asm("v_pk_fma_f32 %0, %1, %2, %0 op_sel:[0,1,0] op_sel_hi:[0,0,1] neg_lo:[1,0,0]"
            : "+v"(t) : "v"(P2), "v"(x0));
        asm("v_pk_fma_f32 %0, %1, %2, %0 op_sel:[0,0,0] op_sel_hi:[0,1,1]"
            : "+v"(t) : "v"(P1), "v"(x0));
        asm("v_pk_mul_f32 %0, %1, %2 op_sel:[0,1] op_sel_hi:[0,0] neg_hi:[1,0]"
            : "=v"(u) : "v"(P2), "v"(x1));
        asm("v_pk_fma_f32 %0, %1, %2, %0 op_sel:[0,0,0] op_sel_hi:[0,1,1]"
            : "+v"(u) : "v"(P1), "v"(x1));
        asm("v_pk_fma_f32 %0, %1, %2, %0 op_sel:[1,1,0] op_sel_hi:[1,0,1] neg_hi:[1,0,0]"
            : "+v"(u) : "v"(P2), "v"(x0));
        asm("v_pk_fma_f32 %0, %1, %2, %0 op_sel:[1,0,0] op_sel_hi:[1,1,1]"
            : "+v"(u) : "v"(P1), "v"(x0));
        x[j0] = t; x[j1] = u;
    }
}

// Padded layout: phys(i) = i + 2*(i>>4).  All pass patterns are affine in the
// register index j (single base VGPR + immediate ds offsets) and hit each
// bank-pair exactly 4x per b64 wave-op; pass C is contiguous 128 B, 16B-aligned.
__global__ __launch_bounds__(256, 4) void qddpm_kernel(
    const float* __restrict__ in_re,
    const float* __restrict__ in_im,
    const float* __restrict__ params,
    const float* __restrict__ uu,
    float* __restrict__ out)
{
    __shared__ v2f    S[SPAD];         // 36 KB, interleaved (re,im), padded layout
    __shared__ float4 gco[48];         // per-gate (cc, cs, ss, sc), g = lay*12+q
    __shared__ float  sprob[16];

    const int b = blockIdx.x;
    const int t = threadIdx.x;
    const float uval = uu[b];          // hoist: hide global latency

    // ---- init: coalesced float4 global loads -> interleaved padded LDS ----
    {
        const float4* re4 = (const float4*)(in_re + (size_t)b * DIM);
        const float4* im4 = (const float4*)(in_im + (size_t)b * DIM);
#pragma unroll
        for (int k = 0; k < 4; ++k) {
            const int g  = k * 256 + t;            // float4 group, amps 4g..4g+3
            const float4 vr = re4[g];
            const float4 vi = im4[g];
            const int pb = g * 4 + (g >> 2) * 2;   // phys(4g); even -> 16B aligned
            float4* dst = (float4*)(S + pb);
            dst[0] = make_float4(vr.x, vi.x, vr.y, vi.y);
            dst[1] = make_float4(vr.z, vi.z, vr.w, vi.w);
        }
        if (t < 48) {                    // gate (lay = t/12, q = t%12)
            const int lay = t / 12, q = t - lay * 12;
            float c1, s1, c2, s2;
            sincosf(params[lay * 24 + q] * 0.5f, &s1, &c1);
            sincosf(params[lay * 24 + 12 + q] * 0.5f, &s2, &c2);
            gco[t] = make_float4(c1 * c2, c1 * s2, s1 * s2, s1 * c2); // (cc,cs,ss,sc)
        }
    }

    // per-thread bases (v2f element indices)
    const int baseA = t + 2 * (t >> 4);                    // pass A: S[baseA + 288*j]
    const int baseB = (t >> 4) * 288 + (t & 15);           // pass B: S[baseB + 18*j]
    const int baseC = t * 18;                              // pass C: S[baseC + j] (contig)

    // CZ-diag sign-bit xor words for this thread's pass-C amps (i = t*16+j)
    int sw[16];
#pragma unroll
    for (int j = 0; j < 16; ++j) {
        const int i = t * 16 + j;
        sw[j] = (__popc(i & (i >> 1) & 0x7FF) & 1) << 31;
    }

    v2f x[16];
    v2f acc2 = (v2f){0.0f, 0.0f};

    __syncthreads();

#pragma unroll 1                        // one layer per iteration: fits L1I
    for (int lay = 0; lay < LAYERS; ++lay) {
        const int gb = lay * 12;

        // ---- pass A: amp bits 11:8 (qubits 0..3) ----
#pragma unroll
        for (int j = 0; j < 16; ++j) x[j] = S[baseA + 288 * j];
        { float4 c;
          c = gco[gb + 3]; gate_pk<0>(x, (v2f){c.x,c.y}, (v2f){c.z,c.w});
          c = gco[gb + 2]; gate_pk<1>(x, (v2f){c.x,c.y}, (v2f){c.z,c.w});
          c = gco[gb + 1]; gate_pk<2>(x, (v2f){c.x,c.y}, (v2f){c.z,c.w});
          c = gco[gb + 0]; gate_pk<3>(x, (v2f){c.x,c.y}, (v2f){c.z,c.w}); }
#pragma unroll
        for (int j = 0; j < 16; ++j) S[baseA + 288 * j] = x[j];
        __syncthreads();

        // ---- pass B: amp bits 7:4 (qubits 4..7) ----
#pragma unroll
        for (int j = 0; j < 16; ++j) x[j] = S[baseB + 18 * j];
        { float4 c;
          c = gco[gb + 7]; gate_pk<0>(x, (v2f){c.x,c.y}, (v2f){c.z,c.w});
          c = gco[gb + 6]; gate_pk<1>(x, (v2f){c.x,c.y}, (v2f){c.z,c.w});
          c = gco[gb + 5]; gate_pk<2>(x, (v2f){c.x,c.y}, (v2f){c.z,c.w});
          c = gco[gb + 4]; gate_pk<3>(x, (v2f){c.x,c.y}, (v2f){c.z,c.w}); }
#pragma unroll
        for (int j = 0; j < 16; ++j) S[baseB + 18 * j] = x[j];
        __syncthreads();

        // ---- pass C: amp bits 3:0 (qubits 8..11) + CZ diag ----
        {
            const float4* src = (const float4*)(S + baseC);   // 16B aligned (t*144)
#pragma unroll
            for (int q = 0; q < 4; ++q) {
                const float4 v = src[q];
                x[2 * q]     = (v2f){v.x, v.y};
                x[2 * q + 1] = (v2f){v.z, v.w};
            }
#pragma unroll
            for (int q = 4; q < 8; ++q) {
                const float4 v = src[q];
                x[2 * q]     = (v2f){v.x, v.y};
                x[2 * q + 1] = (v2f){v.z, v.w};
            }
        }
        { float4 c;
          c = gco[gb + 11]; gate_pk<0>(x, (v2f){c.x,c.y}, (v2f){c.z,c.w});
          c = gco[gb + 10]; gate_pk<1>(x, (v2f){c.x,c.y}, (v2f){c.z,c.w});
          c = gco[gb +  9]; gate_pk<2>(x, (v2f){c.x,c.y}, (v2f){c.z,c.w});
          c = gco[gb +  8]; gate_pk<3>(x, (v2f){c.x,c.y}, (v2f){c.z,c.w}); }
#pragma unroll
        for (int j = 0; j < 16; ++j) {   // CZ: flip sign bits via xor (2 v_xor/amp)
            x[j].x = __uint_as_float(__float_as_uint(x[j].x) ^ sw[j]);
            x[j].y = __uint_as_float(__float_as_uint(x[j].y) ^ sw[j]);
        }
        if (lay == LAYERS - 1) {
#pragma unroll
            for (int j = 0; j < 16; ++j) acc2 += x[j] * x[j];
        }
        {
            float4* dst = (float4*)(S + baseC);
#pragma unroll
            for (int q = 0; q < 8; ++q)
                dst[q] = make_float4(x[2 * q].x, x[2 * q].y, x[2 * q + 1].x, x[2 * q + 1].y);
        }
        // partial reduce before the barrier (independent of S)
        if (lay == LAYERS - 1) {
            float partial = acc2.x + acc2.y;
#pragma unroll
            for (int o = 8; o > 0; o >>= 1)
                partial += __shfl_down(partial, o, 16);
            if ((t & 15) == 0) sprob[t >> 4] = partial;
        }
        __syncthreads();                 // covers S write + sprob write
    }

    // ---- redundant per-thread inverse-CDF sample (no extra barrier) ----
    float cdf[16];
    {
        float a = 0.0f;
#pragma unroll
        for (int i = 0; i < 16; ++i) { a += sprob[i]; cdf[i] = a; }
        const float thresh = uval * a;
        int m = 0;
#pragma unroll
        for (int i = 15; i >= 0; --i) { if (cdf[i] >= thresh) m = i; }
        const float rn = 1.0f / sqrtf(sprob[m]);
        // ---- collapsed, normalized output: [B, 256, 2] ----
        const v2f amp = S[baseA + 288 * m];     // phys(m*256 + t), pass-A pattern
        ((float2*)out)[(size_t)b * 256 + t] = make_float2(amp.x * rn, amp.y * rn);
    }
}

extern "C" void kernel_launch(void* const* d_in, const int* in_sizes, int n_in,
                              void* d_out, int out_size, void* d_ws, size_t ws_size,
                              hipStream_t stream) {
    const float* in_re  = (const float*)d_in[0];
    const float* in_im  = (const float*)d_in[1];
    const float* params = (const float*)d_in[2];
    const float* u      = (const float*)d_in[3];
    float* out = (float*)d_out;
    qddpm_kernel<<<NB, 256, 0, stream>>>(in_re, in_im, params, u, out);
}

// Round 6
// 108.735 us; speedup vs baseline: 1.4555x; 1.0193x over previous
//
#include <hip/hip_runtime.h>
#include <math.h>

#define NTOT   12
#define DIM    4096      // 2^12
#define LAYERS 4
#define NB     1024      // batch
#define SPAD   4608      // phys(i) = i + 2*(i>>4); max 4095+510 = 4605

typedef float v2f __attribute__((ext_vector_type(2)));

// Fused (Ry*Rx) SU(2) gate on local bit G of a 16-amp register block, complex
// interleaved (lo=re, hi=im). Coefficients packed: P1=(cc,cs), P2=(ss,sc).
// 8 v_pk_*_f32 per pair; swaps/negs via op_sel / neg modifiers.
template<int G>
__device__ __forceinline__ void gate_pk(v2f (&x)[16], v2f P1, v2f P2) {
#pragma unroll
    for (int p = 0; p < 8; ++p) {
        const int j0 = ((p >> G) << (G + 1)) | (p & ((1 << G) - 1));
        const int j1 = j0 | (1 << G);
        const v2f x0 = x[j0], x1 = x[j1];
        v2f t, u;
        asm("v_pk_mul_f32 %0, %1, %2 op_sel:[1,1] op_sel_hi:[1,0] neg_hi:[1,0]"
            : "=v"(t) : "v"(P2), "v"(x1));
        asm("v_pk_fma_f32 %0, %1, %2, %0 op_sel:[1,0,0] op_sel_hi:[1,1,1] neg_lo:[1,0,0] neg_hi:[1,0,0]"
            : "+v"(t) : "v"(P1), "v"(x1));
        asm("v_pk_fma_f32 %0, %1, %2, %0 op_sel:[0,1,0] op_sel_hi:[0,0,1] neg_lo:[1,0,0]"
            : "+v"(t) : "v"(P2), "v"(x0));
        asm("v_pk_fma_f32 %0, %1, %2, %0 op_sel:[0,0,0] op_sel_hi:[0,1,1]"
            : "+v"(t) : "v"(P1), "v"(x0));
        asm("v_pk_mul_f32 %0, %1, %2 op_sel:[0,1] op_sel_hi:[0,0] neg_hi:[1,0]"
            : "=v"(u) : "v"(P2), "v"(x1));
        asm("v_pk_fma_f32 %0, %1, %2, %0 op_sel:[0,0,0] op_sel_hi:[0,1,1]"
            : "+v"(u) : "v"(P1), "v"(x1));
        asm("v_pk_fma_f32 %0, %1, %2, %0 op_sel:[1,1,0] op_sel_hi:[1,0,1] neg_hi:[1,0,0]"
            : "+v"(u) : "v"(P2), "v"(x0));
        asm("v_pk_fma_f32 %0, %1, %2, %0 op_sel:[1,0,0] op_sel_hi:[1,1,1]"
            : "+v"(u) : "v"(P1), "v"(x0));
        x[j0] = t; x[j1] = u;
    }
}

// Apply the 4 gates of one partition-group of one layer.
// gco[base+3]->G0, gco[base+2]->G1, gco[base+1]->G2, gco[base+0]->G3.
__device__ __forceinline__ void apply4(v2f (&x)[16], const float4* gco, int base) {
    float4 c;
    c = gco[base + 3]; gate_pk<0>(x, (v2f){c.x, c.y}, (v2f){c.z, c.w});
    c = gco[base + 2]; gate_pk<1>(x, (v2f){c.x, c.y}, (v2f){c.z, c.w});
    c = gco[base + 1]; gate_pk<2>(x, (v2f){c.x, c.y}, (v2f){c.z, c.w});
    c = gco[base + 0]; gate_pk<3>(x, (v2f){c.x, c.y}, (v2f){c.z, c.w});
}

// CZ diagonal: flip sign bits via precomputed xor words (0 or 0x80000000).
__device__ __forceinline__ void applyCZ(v2f (&x)[16], const int (&sw)[16]) {
#pragma unroll
    for (int j = 0; j < 16; ++j) {
        x[j].x = __uint_as_float(__float_as_uint(x[j].x) ^ sw[j]);
        x[j].y = __uint_as_float(__float_as_uint(x[j].y) ^ sw[j]);
    }
}

// Padded layout: phys(i) = i + 2*(i>>4). All pass patterns affine in j, 4
// lanes per bank-pair per wave-op; C-partition contiguous 128 B, 16B-aligned.
// Palindrome schedule: C0|B0|A0+CZ+A1|B1|C1+CZ+C2|B2|A2+CZ+A3|B3|C3+CZ
// => 9 LDS passes, 10 barriers (vs 12/13 for per-layer A|B|C).
__global__ __launch_bounds__(256, 4) void qddpm_kernel(
    const float* __restrict__ in_re,
    const float* __restrict__ in_im,
    const float* __restrict__ params,
    const float* __restrict__ uu,
    float* __restrict__ out)
{
    __shared__ v2f    S[SPAD];         // 36 KB, interleaved (re,im), padded layout
    __shared__ float4 gco[48];         // per-gate (cc, cs, ss, sc), g = lay*12+q
    __shared__ float  sprob[16];

    const int b = blockIdx.x;
    const int t = threadIdx.x;
    const float uval = uu[b];

    // per-thread bases (v2f element indices)
    const int baseA = t + 2 * (t >> 4);            // A: S[baseA + 288*j], amp j*256+t
    const int baseB = (t >> 4) * 288 + (t & 15);   // B: S[baseB + 18*j],  amp (t>>4)*256+j*16+(t&15)
    const int baseC = t * 18;                      // C: S[baseC + j],     amp t*16+j (contig)

    v2f x[16];

    // ---- direct global -> registers, C-partition (64 contiguous B per array) ----
    {
        const float4* re4 = (const float4*)(in_re + (size_t)b * DIM + t * 16);
        const float4* im4 = (const float4*)(in_im + (size_t)b * DIM + t * 16);
#pragma unroll
        for (int q = 0; q < 4; ++q) {
            const float4 vr = re4[q];
            const float4 vi = im4[q];
            x[4 * q + 0] = (v2f){vr.x, vi.x};
            x[4 * q + 1] = (v2f){vr.y, vi.y};
            x[4 * q + 2] = (v2f){vr.z, vi.z};
            x[4 * q + 3] = (v2f){vr.w, vi.w};
        }
    }
    if (t < 48) {                        // gate (lay = t/12, q = t%12)
        const int lay = t / 12, q = t - lay * 12;
        float c1, s1, c2, s2;
        sincosf(params[lay * 24 + q] * 0.5f, &s1, &c1);
        sincosf(params[lay * 24 + 12 + q] * 0.5f, &s2, &c2);
        gco[t] = make_float4(c1 * c2, c1 * s2, s1 * s2, s1 * c2); // (cc,cs,ss,sc)
    }

    // CZ sign-bit xor words for both partitions used for CZ application
    int swA[16], swC[16];
#pragma unroll
    for (int j = 0; j < 16; ++j) {
        const int iC = t * 16 + j;           // C-partition amp
        swC[j] = (__popc(iC & (iC >> 1) & 0x7FF) & 1) << 31;
        const int iA = j * 256 + t;          // A-partition amp
        swA[j] = (__popc(iA & (iA >> 1) & 0x7FF) & 1) << 31;
    }

    __syncthreads();                     // (1) gco ready; x stays in registers

    // ---- P1: C gates layer0 (q8..q11) ----
    apply4(x, gco, 0 * 12 + 8);
    {
        float4* dst = (float4*)(S + baseC);
#pragma unroll
        for (int q = 0; q < 8; ++q)
            dst[q] = make_float4(x[2 * q].x, x[2 * q].y, x[2 * q + 1].x, x[2 * q + 1].y);
    }
    __syncthreads();                     // (2)

    // ---- P2: B gates layer0 (q4..q7) ----
#pragma unroll
    for (int j = 0; j < 16; ++j) x[j] = S[baseB + 18 * j];
    apply4(x, gco, 0 * 12 + 4);
#pragma unroll
    for (int j = 0; j < 16; ++j) S[baseB + 18 * j] = x[j];
    __syncthreads();                     // (3)

    // ---- P3: A layer0 + CZ0 + A layer1 ----
#pragma unroll
    for (int j = 0; j < 16; ++j) x[j] = S[baseA + 288 * j];
    apply4(x, gco, 0 * 12 + 0);
    applyCZ(x, swA);
    apply4(x, gco, 1 * 12 + 0);
#pragma unroll
    for (int j = 0; j < 16; ++j) S[baseA + 288 * j] = x[j];
    __syncthreads();                     // (4)

    // ---- P4: B layer1 ----
#pragma unroll
    for (int j = 0; j < 16; ++j) x[j] = S[baseB + 18 * j];
    apply4(x, gco, 1 * 12 + 4);
#pragma unroll
    for (int j = 0; j < 16; ++j) S[baseB + 18 * j] = x[j];
    __syncthreads();                     // (5)

    // ---- P5: C layer1 + CZ1 + C layer2 ----
    {
        const float4* src = (const float4*)(S + baseC);
#pragma unroll
        for (int q = 0; q < 8; ++q) {
            const float4 v = src[q];
            x[2 * q]     = (v2f){v.x, v.y};
            x[2 * q + 1] = (v2f){v.z, v.w};
        }
    }
    apply4(x, gco, 1 * 12 + 8);
    applyCZ(x, swC);
    apply4(x, gco, 2 * 12 + 8);
    {
        float4* dst = (float4*)(S + baseC);
#pragma unroll
        for (int q = 0; q < 8; ++q)
            dst[q] = make_float4(x[2 * q].x, x[2 * q].y, x[2 * q + 1].x, x[2 * q + 1].y);
    }
    __syncthreads();                     // (6)

    // ---- P6: B layer2 ----
#pragma unroll
    for (int j = 0; j < 16; ++j) x[j] = S[baseB + 18 * j];
    apply4(x, gco, 2 * 12 + 4);
#pragma unroll
    for (int j = 0; j < 16; ++j) S[baseB + 18 * j] = x[j];
    __syncthreads();                     // (7)

    // ---- P7: A layer2 + CZ2 + A layer3 ----
#pragma unroll
    for (int j = 0; j < 16; ++j) x[j] = S[baseA + 288 * j];
    apply4(x, gco, 2 * 12 + 0);
    applyCZ(x, swA);
    apply4(x, gco, 3 * 12 + 0);
#pragma unroll
    for (int j = 0; j < 16; ++j) S[baseA + 288 * j] = x[j];
    __syncthreads();                     // (8)

    // ---- P8: B layer3 ----
#pragma unroll
    for (int j = 0; j < 16; ++j) x[j] = S[baseB + 18 * j];
    apply4(x, gco, 3 * 12 + 4);
#pragma unroll
    for (int j = 0; j < 16; ++j) S[baseB + 18 * j] = x[j];
    __syncthreads();                     // (9)

    // ---- P9: C layer3 + CZ3 + probs ----
    {
        const float4* src = (const float4*)(S + baseC);
#pragma unroll
        for (int q = 0; q < 8; ++q) {
            const float4 v = src[q];
            x[2 * q]     = (v2f){v.x, v.y};
            x[2 * q + 1] = (v2f){v.z, v.w};
        }
    }
    apply4(x, gco, 3 * 12 + 8);
    applyCZ(x, swC);
    {
        v2f acc2 = (v2f){0.0f, 0.0f};
#pragma unroll
        for (int j = 0; j < 16; ++j) acc2 += x[j] * x[j];
        float4* dst = (float4*)(S + baseC);
#pragma unroll
        for (int q = 0; q < 8; ++q)
            dst[q] = make_float4(x[2 * q].x, x[2 * q].y, x[2 * q + 1].x, x[2 * q + 1].y);
        // this thread's 16 amps (i = t*16+j) all belong to ancilla outcome t>>4
        float partial = acc2.x + acc2.y;
#pragma unroll
        for (int o = 8; o > 0; o >>= 1)
            partial += __shfl_down(partial, o, 16);
        if ((t & 15) == 0) sprob[t >> 4] = partial;
    }
    __syncthreads();                     // (10) covers S write + sprob

    // ---- redundant per-thread inverse-CDF sample + output [B, 256, 2] ----
    {
        float cdf[16];
        float a = 0.0f;
#pragma unroll
        for (int i = 0; i < 16; ++i) { a += sprob[i]; cdf[i] = a; }
        const float thresh = uval * a;
        int m = 0;
#pragma unroll
        for (int i = 15; i >= 0; --i) { if (cdf[i] >= thresh) m = i; }
        const float rn = 1.0f / sqrtf(sprob[m]);
        const v2f amp = S[baseA + 288 * m];     // phys(m*256 + t), A-pattern
        ((float2*)out)[(size_t)b * 256 + t] = make_float2(amp.x * rn, amp.y * rn);
    }
}

extern "C" void kernel_launch(void* const* d_in, const int* in_sizes, int n_in,
                              void* d_out, int out_size, void* d_ws, size_t ws_size,
                              hipStream_t stream) {
    const float* in_re  = (const float*)d_in[0];
    const float* in_im  = (const float*)d_in[1];
    const float* params = (const float*)d_in[2];
    const float* u      = (const float*)d_in[3];
    float* out = (float*)d_out;
    qddpm_kernel<<<NB, 256, 0, stream>>>(in_re, in_im, params, u, out);
}